// Round 12
// baseline (195.488 us; speedup 1.0000x reference)
//
#include <hip/hip_runtime.h>
#include <hip/hip_bf16.h>

#define NN 100000
#define EE 3200000
#define GG 128
#define IN_DIM 16
#define HDIM 64
#define CDIM 4

#define RN 256                    // nodes per bucket
#define NB ((NN + RN - 1) / RN)   // 391 buckets
#define CH 8192                   // edges per partition block

typedef unsigned short u16;
typedef unsigned int u32;
typedef __attribute__((ext_vector_type(8))) short bf16x8;
typedef __attribute__((ext_vector_type(4))) float f32x4;

__device__ __forceinline__ float bf_lo(u32 w) { return __uint_as_float(w << 16); }
__device__ __forceinline__ float bf_hi(u32 w) { return __uint_as_float(w & 0xFFFF0000u); }
__device__ __forceinline__ u16 f2bf(float f) {
    u32 x = __float_as_uint(f);
    return (u16)((x + 0x7FFFu + ((x >> 16) & 1u)) >> 16);   // RNE
}
__device__ __forceinline__ float rdlane(float v, int lane) {
    return __int_as_float(__builtin_amdgcn_readlane(__float_as_int(v), lane));
}

// ---------------- bucket histogram ----------------

__global__ __launch_bounds__(512) void bhist_k(const int* __restrict__ dst,
                                               int* __restrict__ bcnt) {
    __shared__ int hist[NB];
    int t = threadIdx.x;
    long e0 = (long)blockIdx.x * CH;
    int cnt = (int)min((long)CH, (long)EE - e0);
    for (int i = t; i < NB; i += 512) hist[i] = 0;
    __syncthreads();
    for (int i = t; i < cnt; i += 512) atomicAdd(&hist[dst[e0 + i] >> 8], 1);
    __syncthreads();
    for (int i = t; i < NB; i += 512) {
        int v = hist[i];
        if (v > 0) atomicAdd(&bcnt[i], v);
    }
}

__global__ void bucketscan_k(const int* __restrict__ bcnt, int* __restrict__ bucketBase,
                             int* __restrict__ gcursor) {
    __shared__ int s[512];
    int t = threadIdx.x;
    int c = (t < NB) ? bcnt[t] : 0;
    s[t] = c;
    __syncthreads();
    for (int off = 1; off < 512; off <<= 1) {
        int v = (t >= off) ? s[t - off] : 0;
        __syncthreads();
        s[t] += v;
        __syncthreads();
    }
    if (t < NB) {
        int base = s[t] - c;
        bucketBase[t] = base;
        gcursor[t] = base;
    }
    if (t == 0) bucketBase[NB] = EE;
}

// ---------------- partition: edges -> bucket-grouped packed pairs ----------------

__global__ __launch_bounds__(512) void partition_k(const int* __restrict__ src,
                                                   const int* __restrict__ dst,
                                                   int* __restrict__ gcursor,
                                                   u32* __restrict__ pairs) {
    __shared__ int hist[NB];
    __shared__ int lbase[NB];
    __shared__ int gbase[NB];
    __shared__ int scanbuf[512];
    __shared__ u32 stag[CH];
    __shared__ u16 stagb[CH];
    int t = threadIdx.x;
    long e0 = (long)blockIdx.x * CH;
    int cnt = (int)min((long)CH, (long)EE - e0);

    for (int i = t; i < NB; i += 512) hist[i] = 0;
    __syncthreads();

    int myb[16], myloc[16];
    u32 myp[16];
#pragma unroll
    for (int r = 0; r < 16; ++r) {
        int i = t + (r << 9);
        if (i < cnt) {
            int s = src[e0 + i], d = dst[e0 + i];
            int b = d >> 8;
            myb[r] = b;
            myp[r] = ((u32)s << 8) | (u32)(d & 255);
            myloc[r] = atomicAdd(&hist[b], 1);
        } else {
            myb[r] = -1;
            myloc[r] = 0;
            myp[r] = 0;
        }
    }
    __syncthreads();

    scanbuf[t] = (t < NB) ? hist[t] : 0;
    __syncthreads();
    for (int off = 1; off < 512; off <<= 1) {
        int v = (t >= off) ? scanbuf[t - off] : 0;
        __syncthreads();
        scanbuf[t] += v;
        __syncthreads();
    }
    if (t < NB) {
        lbase[t] = scanbuf[t] - hist[t];
        gbase[t] = (hist[t] > 0) ? atomicAdd(&gcursor[t], hist[t]) : 0;
    }
    __syncthreads();

#pragma unroll
    for (int r = 0; r < 16; ++r) {
        if (myb[r] >= 0) {
            int pos = lbase[myb[r]] + myloc[r];
            stag[pos] = myp[r];
            stagb[pos] = (u16)myb[r];
        }
    }
    __syncthreads();

    for (int i = t; i < cnt; i += 512) {
        int b = stagb[i];
        pairs[gbase[b] + (i - lbase[b])] = stag[i];
    }
}

// ---------------- per-bucket CSR fill + dinv + fused xs (x * dinv, bf16) -------------

__global__ __launch_bounds__(512) void csrfill_k(const int* __restrict__ bucketBase,
                                                 const u32* __restrict__ pairs,
                                                 const float* __restrict__ x,
                                                 int* __restrict__ rowptr,
                                                 float* __restrict__ dinv,
                                                 int* __restrict__ srcS,
                                                 u16* __restrict__ xs) {
    __shared__ int sb[256];
    __shared__ int sdeg[256];
    __shared__ int lcur[256];
    __shared__ float sdinv[256];
    int b = blockIdx.x, t = threadIdx.x;
    int n0 = b << 8;
    int gb = bucketBase[b];
    int gend = bucketBase[b + 1];
    int nvalid = min(256, NN - n0);

    if (t < 256) sb[t] = 0;
    __syncthreads();

    for (int idx = gb + t; idx < gend; idx += 512) atomicAdd(&sb[pairs[idx] & 255u], 1);
    __syncthreads();

    int d = (t < 256) ? sb[t] : 0;
    if (t < 256) {
        sdeg[t] = d;
        float dn = rsqrtf((float)(d + 1));
        sdinv[t] = dn;
        int n = n0 + t;
        if (n < NN) dinv[n] = dn;
    }
    __syncthreads();
    for (int off = 1; off < 256; off <<= 1) {
        int v = 0;
        if (t < 256 && t >= off) v = sb[t - off];
        __syncthreads();
        if (t < 256) sb[t] += v;
        __syncthreads();
    }
    if (t < 256) {
        int excl = sb[t] - sdeg[t];
        int n = n0 + t;
        if (n < NN) rowptr[n] = gb + excl;
        lcur[t] = excl;
    }
    if (b == 0 && t == 0) rowptr[NN] = EE;
    __syncthreads();

    for (int idx = gb + t; idx < gend; idx += 512) {
        u32 p = pairs[idx];
        int dl = (int)(p & 255u);
        int slot = atomicAdd(&lcur[dl], 1);
        srcS[gb + slot] = (int)(p >> 8);
    }

    // fused xs: 256 nodes * 16 feats = 1024 float4; thread t does 2
    for (int q = t; q < nvalid * 4; q += 512) {
        int nloc = q >> 2;
        float dn = sdinv[nloc];
        float4 v = ((const float4*)x)[(size_t)n0 * 4 + q];
        u32 p0 = (u32)f2bf(v.x * dn) | ((u32)f2bf(v.y * dn) << 16);
        u32 p1 = (u32)f2bf(v.z * dn) | ((u32)f2bf(v.w * dn) << 16);
        uint2 pk; pk.x = p0; pk.y = p1;
        ((uint2*)xs)[(size_t)n0 * 4 + q] = pk;
    }
}

#define ACCUM8(acc, v)                       \
    {                                        \
        acc[0] += bf_lo(v.x);                \
        acc[1] += bf_hi(v.x);                \
        acc[2] += bf_lo(v.y);                \
        acc[3] += bf_hi(v.y);                \
        acc[4] += bf_lo(v.z);                \
        acc[5] += bf_hi(v.z);                \
        acc[6] += bf_lo(v.w);                \
        acc[7] += bf_hi(v.w);                \
    }

// folded reduce over lane-bit masks mA<mB<mC: 8 accs -> 1 value per lane.
#define FOLD3(res, acc, mA, mB, mC)                                   \
    {                                                                 \
        float tj[4], uj[2];                                           \
        _Pragma("unroll")                                             \
        for (int j = 0; j < 4; j++) {                                 \
            float lo = acc[j], hi = acc[j + 4];                       \
            float snd = (lane & mA) ? lo : hi;                        \
            float rcv = __shfl_xor(snd, mA);                          \
            tj[j] = (lane & mA) ? hi + rcv : lo + rcv;                \
        }                                                             \
        _Pragma("unroll")                                             \
        for (int j = 0; j < 2; j++) {                                 \
            float lo = tj[j], hi = tj[j + 2];                         \
            float snd = (lane & mB) ? lo : hi;                        \
            float rcv = __shfl_xor(snd, mB);                          \
            uj[j] = (lane & mB) ? hi + rcv : lo + rcv;                \
        }                                                             \
        {                                                             \
            float lo = uj[0], hi = uj[1];                             \
            float snd = (lane & mC) ? lo : hi;                        \
            float rcv = __shfl_xor(snd, mC);                          \
            res = (lane & mC) ? hi + rcv : lo + rcv;                  \
        }                                                             \
    }

// ---------------- pass 1 fused: agg16 + @W1 + relu + *dinv -> LDS tile -> MFMA @W2 ---
// 8 waves/block, 2 nodes/wave -> 16 nodes/block = one 16x64 MFMA A-tile.
// gather lanes: c = lane&1 (16B chunk of 32B row), r = lane>>1 (32 edge slots)
// MFMA (wave 0): A row=lane&15, k=(lane>>4)*8+j; C col=lane&15, row=(lane>>4)*4+q.

__global__ __launch_bounds__(512) void aggxg_k(const u16* __restrict__ xs,
                                               const int* __restrict__ rowptr,
                                               const int* __restrict__ srcS,
                                               const float* __restrict__ dinv,
                                               const float* __restrict__ b1,
                                               const float* __restrict__ W1,
                                               const float* __restrict__ W2,
                                               u16* __restrict__ h2s) {
    __shared__ u16 atile[16][72];   // stride 72 shorts = 144 B: 16B-aligned rows, 2-way banks
    int t = threadIdx.x;
    int lane = t & 63, w = t >> 6;
    int c = lane & 1, r = lane >> 1;
    int nb = blockIdx.x * 16;
    int n0 = nb + w * 2;
    int n1 = n0 + 1;
    int L4 = lane >> 4, L15 = lane & 15;

    // W2 fragments (wave 0 only uses them)
    bf16x8 bfrag[4][2];
    if (w == 0) {
#pragma unroll
        for (int nt = 0; nt < 4; ++nt)
#pragma unroll
            for (int s = 0; s < 2; ++s)
#pragma unroll
                for (int j = 0; j < 8; ++j) {
                    int k = s * 32 + L4 * 8 + j;
                    bfrag[nt][s][j] = (short)f2bf(W2[k * HDIM + nt * 16 + L15]);
                }
    }

    float w1c[16];
#pragma unroll
    for (int k = 0; k < 16; k++) w1c[k] = W1[k * HDIM + lane];
    float b1l = b1[lane];

    int beg0 = rowptr[n0], end0 = rowptr[n0 + 1], end1 = rowptr[n0 + 2];
    int beg1 = end0;
    float dn0 = dinv[n0], dn1 = dinv[n1];

    float acc0[8] = {0, 0, 0, 0, 0, 0, 0, 0};
    float acc1[8] = {0, 0, 0, 0, 0, 0, 0, 0};
    if (r == 0) {   // self-loops
        uint4 v0 = *(const uint4*)(xs + ((size_t)n0 << 4) + (c << 3));
        uint4 v1 = *(const uint4*)(xs + ((size_t)n1 << 4) + (c << 3));
        ACCUM8(acc0, v0);
        ACCUM8(acc1, v1);
    }
    int itmax = max((end0 - beg0 + 31) >> 5, (end1 - beg1 + 31) >> 5);
    for (int it = 0; it < itmax; ++it) {
        int eA = beg0 + (it << 5) + r;
        int eB = beg1 + (it << 5) + r;
        int iA = srcS[eA < end0 ? eA : beg0];
        int iB = srcS[eB < end1 ? eB : beg1];
        uint4 vA = *(const uint4*)(xs + ((size_t)iA << 4) + (c << 3));
        uint4 vB = *(const uint4*)(xs + ((size_t)iB << 4) + (c << 3));
        if (eA < end0) ACCUM8(acc0, vA);
        if (eB < end1) ACCUM8(acc1, vB);
    }

    float v0, v1;
    FOLD3(v0, acc0, 2, 4, 8);
    FOLD3(v1, acc1, 2, 4, 8);
    v0 += __shfl_xor(v0, 16); v0 += __shfl_xor(v0, 32);
    v1 += __shfl_xor(v1, 16); v1 += __shfl_xor(v1, 32);
    // lane holds agg16 feature (lane&1)*8 + sel(bits1..3)

    float dot0 = 0.f, dot1 = 0.f;
#pragma unroll
    for (int k = 0; k < 16; k++) {
        int L = ((k >> 3) & 1) | (((k >> 2) & 1) << 1) | (((k >> 1) & 1) << 2) | ((k & 1) << 3);
        dot0 = fmaf(rdlane(v0, L), w1c[k], dot0);
        dot1 = fmaf(rdlane(v1, L), w1c[k], dot1);
    }
    float h0 = fmaxf(fmaf(dot0, dn0, b1l), 0.f);
    float h1 = fmaxf(fmaf(dot1, dn1, b1l), 0.f);

    atile[w * 2][lane] = f2bf(h0 * dn0);
    atile[w * 2 + 1][lane] = f2bf(h1 * dn1);
    __syncthreads();

    if (w == 0) {
        bf16x8 a0 = *(const bf16x8*)&atile[L15][L4 * 8];
        bf16x8 a1 = *(const bf16x8*)&atile[L15][L4 * 8 + 32];
        f32x4 cc[4];
#pragma unroll
        for (int nt = 0; nt < 4; ++nt) {
            cc[nt] = (f32x4){0.f, 0.f, 0.f, 0.f};
            cc[nt] = __builtin_amdgcn_mfma_f32_16x16x32_bf16(a0, bfrag[nt][0], cc[nt], 0, 0, 0);
            cc[nt] = __builtin_amdgcn_mfma_f32_16x16x32_bf16(a1, bfrag[nt][1], cc[nt], 0, 0, 0);
        }
#pragma unroll
        for (int q = 0; q < 4; ++q) {
            int row = L4 * 4 + q;
            size_t base = (size_t)(nb + row) * HDIM + L15;
#pragma unroll
            for (int nt = 0; nt < 4; ++nt) h2s[base + nt * 16] = f2bf(cc[nt][q]);
        }
    }
}

// ---------------- pass 2: 64-dim gather + relu + pool with LDS pool pre-reduction ----

__global__ __launch_bounds__(512) void agg_pool_k(const u16* __restrict__ hs,
                                                  const int* __restrict__ rowptr,
                                                  const int* __restrict__ srcS,
                                                  const float* __restrict__ dinv,
                                                  const float* __restrict__ b2,
                                                  const int* __restrict__ batch,
                                                  float* __restrict__ g) {
    __shared__ float gacc[4][HDIM];
    __shared__ int s_g0, s_gmax;
    int t = threadIdx.x;
    int lane = t & 63, w = t >> 6;
    int nbase = blockIdx.x * 32;

    if (t < 4 * HDIM) gacc[t >> 6][t & 63] = 0.f;
    if (t == 0) { s_g0 = batch[nbase]; s_gmax = 0; }
    __syncthreads();
    int g0 = s_g0;

    int r = lane >> 3, c = lane & 7;
    int f = (c << 3) + ((lane & 8) ? 4 : 0) + ((lane & 16) ? 2 : 0) + ((lane & 32) ? 1 : 0);
    float b2f = b2[f];

    for (int ni = 0; ni < 4; ++ni) {
        int n = nbase + w * 4 + ni;
        int beg = rowptr[n], end = rowptr[n + 1];
        float acc[8] = {0.f, 0.f, 0.f, 0.f, 0.f, 0.f, 0.f, 0.f};
        if (r == 0) {   // self-loop
            uint4 v = *(const uint4*)(hs + ((size_t)n << 6) + (c << 3));
            ACCUM8(acc, v);
        }
        for (int e0 = beg; e0 < end; e0 += 32) {
            int eA = e0 + r, eB = eA + 8, eC = eA + 16, eD = eA + 24;
            int iA = srcS[eA < end ? eA : beg];
            int iB = srcS[eB < end ? eB : beg];
            int iC = srcS[eC < end ? eC : beg];
            int iD = srcS[eD < end ? eD : beg];
            uint4 vA = *(const uint4*)(hs + ((size_t)iA << 6) + (c << 3));
            uint4 vB = *(const uint4*)(hs + ((size_t)iB << 6) + (c << 3));
            uint4 vC = *(const uint4*)(hs + ((size_t)iC << 6) + (c << 3));
            uint4 vD = *(const uint4*)(hs + ((size_t)iD << 6) + (c << 3));
            if (eA < end) ACCUM8(acc, vA);
            if (eB < end) ACCUM8(acc, vB);
            if (eC < end) ACCUM8(acc, vC);
            if (eD < end) ACCUM8(acc, vD);
        }
        float red;
        FOLD3(red, acc, 8, 16, 32);
        float v = fmaf(red, dinv[n], b2f);
        v = fmaxf(v, 0.f);
        int gi = batch[n] - g0;
        if (gi < 4) {
            atomicAdd(&gacc[gi][f], v);
            if (lane == 0) atomicMax(&s_gmax, gi);
        } else {
            unsafeAtomicAdd(&g[(size_t)batch[n] * HDIM + f], v);
        }
    }
    __syncthreads();
    if (t < 4 * HDIM) {
        int slot = t >> 6, ff = t & 63;
        if (slot <= s_gmax) unsafeAtomicAdd(&g[(size_t)(g0 + slot) * HDIM + ff], gacc[slot][ff]);
    }
}

__global__ void final_k(const float* __restrict__ g, const float* __restrict__ Wl,
                        const float* __restrict__ bl, float* __restrict__ out) {
    int t = threadIdx.x;
    int gi = t >> 2, cc = t & 3;
    float acc = bl[cc];
#pragma unroll
    for (int k = 0; k < HDIM; k++) acc = fmaf(g[gi * HDIM + k], Wl[k * CDIM + cc], acc);
    out[gi * CDIM + cc] = acc;
}

// ---------------- launch ----------------

extern "C" void kernel_launch(void* const* d_in, const int* in_sizes, int n_in,
                              void* d_out, int out_size, void* d_ws, size_t ws_size,
                              hipStream_t stream) {
    const float* x   = (const float*)d_in[0];
    const int*   ei  = (const int*)d_in[1];
    const int*   src = ei;
    const int*   dst = ei + EE;
    const int*   batch = (const int*)d_in[2];
    const float* W1 = (const float*)d_in[3];
    const float* b1 = (const float*)d_in[4];
    const float* W2 = (const float*)d_in[5];
    const float* b2 = (const float*)d_in[6];
    const float* Wl = (const float*)d_in[7];
    const float* bl = (const float*)d_in[8];
    float* out = (float*)d_out;

    char* w = (char*)d_ws;
    auto alloc = [&](size_t bytes) -> char* {
        char* p = w;
        w += (bytes + 255) & ~(size_t)255;
        return p;
    };
    int*   bcnt       = (int*)alloc((size_t)NB * 4);
    int*   bucketBase = (int*)alloc((size_t)(NB + 1) * 4);
    int*   gcursor    = (int*)alloc((size_t)NB * 4);
    u32*   pairs      = (u32*)alloc((size_t)EE * 4);
    int*   srcS       = (int*)alloc((size_t)EE * 4);
    int*   rowptr     = (int*)alloc((size_t)(NN + 1) * 4);
    float* dinv       = (float*)alloc((size_t)NN * 4);
    u16*   xs         = (u16*)alloc((size_t)NN * IN_DIM * 2);
    u16*   h2s        = (u16*)alloc((size_t)NN * HDIM * 2);
    float* g          = (float*)alloc((size_t)GG * HDIM * 4);

    hipMemsetAsync(bcnt, 0, (size_t)NB * 4, stream);
    hipMemsetAsync(g, 0, (size_t)GG * HDIM * 4, stream);

    const int NCHUNK = (EE + CH - 1) / CH;
    bhist_k<<<NCHUNK, 512, 0, stream>>>(dst, bcnt);
    bucketscan_k<<<1, 512, 0, stream>>>(bcnt, bucketBase, gcursor);
    partition_k<<<NCHUNK, 512, 0, stream>>>(src, dst, gcursor, pairs);
    csrfill_k<<<NB, 512, 0, stream>>>(bucketBase, pairs, x, rowptr, dinv, srcS, xs);

    aggxg_k<<<NN / 16, 512, 0, stream>>>(xs, rowptr, srcS, dinv, b1, W1, W2, h2s);
    agg_pool_k<<<(NN + 31) / 32, 512, 0, stream>>>(h2s, rowptr, srcS, dinv, b2, batch, g);
    final_k<<<1, 512, 0, stream>>>(g, Wl, bl, out);
}

// Round 13
// 179.869 us; speedup vs baseline: 1.0868x; 1.0868x over previous
//
#include <hip/hip_runtime.h>
#include <hip/hip_bf16.h>

#define NN 100000
#define EE 3200000
#define GG 128
#define IN_DIM 16
#define HDIM 64
#define CDIM 4

#define RN 256                    // nodes per bucket
#define NB ((NN + RN - 1) / RN)   // 391 buckets
#define CH 8192                   // edges per partition block

typedef unsigned char u8;
typedef unsigned short u16;
typedef unsigned int u32;
typedef __attribute__((ext_vector_type(8))) short bf16x8;
typedef __attribute__((ext_vector_type(4))) float f32x4;
typedef __attribute__((ext_vector_type(2))) float f32x2;

#if defined(__has_builtin)
#if __has_builtin(__builtin_amdgcn_cvt_pk_f32_fp8) && __has_builtin(__builtin_amdgcn_cvt_pk_fp8_f32)
#define HAS_FP8_CVT 1
#endif
#endif
#ifndef HAS_FP8_CVT
#define HAS_FP8_CVT 0
#endif

__device__ __forceinline__ float bf_lo(u32 w) { return __uint_as_float(w << 16); }
__device__ __forceinline__ float bf_hi(u32 w) { return __uint_as_float(w & 0xFFFF0000u); }
__device__ __forceinline__ u16 f2bf(float f) {
    u32 x = __float_as_uint(f);
    return (u16)((x + 0x7FFFu + ((x >> 16) & 1u)) >> 16);   // RNE
}
__device__ __forceinline__ float rdlane(float v, int lane) {
    return __int_as_float(__builtin_amdgcn_readlane(__float_as_int(v), lane));
}

// ---- fp8 e4m3 helpers (OCP on gfx950) ----
__device__ __forceinline__ u8 f2fp8(float f) {
#if HAS_FP8_CVT
    return (u8)(__builtin_amdgcn_cvt_pk_fp8_f32(f, 0.f, 0, false) & 0xFF);
#else
    u32 x = __float_as_uint(f);
    u32 s = (x >> 24) & 0x80u;
    float a = __uint_as_float(x & 0x7FFFFFFFu);
    if (a >= 448.f) return (u8)(s | 0x7E);
    if (a < 0.0009765625f) return (u8)s;
    int e = (int)((x >> 23) & 0xFF) - 127;
    if (e < -6) {
        int m = (int)(a * 512.f + 0.5f);
        return (u8)(s | (u32)m);
    }
    u32 mant = x & 0x7FFFFFu;
    u32 m3 = (mant + 0x7FFFFu + ((mant >> 20) & 1u)) >> 20;
    u32 ee = (u32)(e + 7);
    if (m3 == 8u) { m3 = 0u; ee += 1u; }
    if (ee >= 16u) return (u8)(s | 0x7E);
    return (u8)(s | (ee << 3) | m3);
#endif
}

#if HAS_FP8_CVT
#define ACC16(acc, v)                                                   \
    {                                                                   \
        _Pragma("unroll")                                               \
        for (int h = 0; h < 4; ++h) {                                   \
            u32 wv = ((const u32*)&(v))[h];                             \
            f32x2 lo = __builtin_amdgcn_cvt_pk_f32_fp8(wv, false);      \
            f32x2 hi = __builtin_amdgcn_cvt_pk_f32_fp8(wv, true);       \
            acc[h * 4 + 0] += lo.x;                                     \
            acc[h * 4 + 1] += lo.y;                                     \
            acc[h * 4 + 2] += hi.x;                                     \
            acc[h * 4 + 3] += hi.y;                                     \
        }                                                               \
    }
#else
__device__ __forceinline__ float fp82f(u8 b) {
    u32 s = ((u32)(b & 0x80u)) << 24;
    u32 em = b & 0x7Fu;
    float v;
    if ((em >> 3) == 0u) v = (float)em * 0.001953125f;
    else v = __uint_as_float((((em >> 3) + 120u) << 23) | ((em & 7u) << 20));
    return __uint_as_float(__float_as_uint(v) | s);
}
#define ACC16(acc, v)                                                   \
    {                                                                   \
        _Pragma("unroll")                                               \
        for (int h = 0; h < 4; ++h) {                                   \
            u32 wv = ((const u32*)&(v))[h];                             \
            acc[h * 4 + 0] += fp82f((u8)(wv & 0xFF));                   \
            acc[h * 4 + 1] += fp82f((u8)((wv >> 8) & 0xFF));            \
            acc[h * 4 + 2] += fp82f((u8)((wv >> 16) & 0xFF));           \
            acc[h * 4 + 3] += fp82f((u8)(wv >> 24));                    \
        }                                                               \
    }
#endif

// ---------------- bucket histogram ----------------

__global__ __launch_bounds__(512) void bhist_k(const int* __restrict__ dst,
                                               int* __restrict__ bcnt) {
    __shared__ int hist[NB];
    int t = threadIdx.x;
    long e0 = (long)blockIdx.x * CH;
    int cnt = (int)min((long)CH, (long)EE - e0);
    for (int i = t; i < NB; i += 512) hist[i] = 0;
    __syncthreads();
    for (int i = t; i < cnt; i += 512) atomicAdd(&hist[dst[e0 + i] >> 8], 1);
    __syncthreads();
    for (int i = t; i < NB; i += 512) {
        int v = hist[i];
        if (v > 0) atomicAdd(&bcnt[i], v);
    }
}

__global__ void bucketscan_k(const int* __restrict__ bcnt, int* __restrict__ bucketBase,
                             int* __restrict__ gcursor) {
    __shared__ int s[512];
    int t = threadIdx.x;
    int c = (t < NB) ? bcnt[t] : 0;
    s[t] = c;
    __syncthreads();
    for (int off = 1; off < 512; off <<= 1) {
        int v = (t >= off) ? s[t - off] : 0;
        __syncthreads();
        s[t] += v;
        __syncthreads();
    }
    if (t < NB) {
        int base = s[t] - c;
        bucketBase[t] = base;
        gcursor[t] = base;
    }
    if (t == 0) bucketBase[NB] = EE;
}

// ---------------- partition: edges -> bucket-grouped packed pairs ----------------

__global__ __launch_bounds__(512) void partition_k(const int* __restrict__ src,
                                                   const int* __restrict__ dst,
                                                   int* __restrict__ gcursor,
                                                   u32* __restrict__ pairs) {
    __shared__ int hist[NB];
    __shared__ int lbase[NB];
    __shared__ int gbase[NB];
    __shared__ int scanbuf[512];
    __shared__ u32 stag[CH];
    __shared__ u16 stagb[CH];
    int t = threadIdx.x;
    long e0 = (long)blockIdx.x * CH;
    int cnt = (int)min((long)CH, (long)EE - e0);

    for (int i = t; i < NB; i += 512) hist[i] = 0;
    __syncthreads();

    int myb[16], myloc[16];
    u32 myp[16];
#pragma unroll
    for (int r = 0; r < 16; ++r) {
        int i = t + (r << 9);
        if (i < cnt) {
            int s = src[e0 + i], d = dst[e0 + i];
            int b = d >> 8;
            myb[r] = b;
            myp[r] = ((u32)s << 8) | (u32)(d & 255);
            myloc[r] = atomicAdd(&hist[b], 1);
        } else {
            myb[r] = -1;
            myloc[r] = 0;
            myp[r] = 0;
        }
    }
    __syncthreads();

    scanbuf[t] = (t < NB) ? hist[t] : 0;
    __syncthreads();
    for (int off = 1; off < 512; off <<= 1) {
        int v = (t >= off) ? scanbuf[t - off] : 0;
        __syncthreads();
        scanbuf[t] += v;
        __syncthreads();
    }
    if (t < NB) {
        lbase[t] = scanbuf[t] - hist[t];
        gbase[t] = (hist[t] > 0) ? atomicAdd(&gcursor[t], hist[t]) : 0;
    }
    __syncthreads();

#pragma unroll
    for (int r = 0; r < 16; ++r) {
        if (myb[r] >= 0) {
            int pos = lbase[myb[r]] + myloc[r];
            stag[pos] = myp[r];
            stagb[pos] = (u16)myb[r];
        }
    }
    __syncthreads();

    for (int i = t; i < cnt; i += 512) {
        int b = stagb[i];
        pairs[gbase[b] + (i - lbase[b])] = stag[i];
    }
}

// ---------------- per-bucket CSR fill ----------------

__global__ __launch_bounds__(512) void csrfill_k(const int* __restrict__ bucketBase,
                                                 const u32* __restrict__ pairs,
                                                 int* __restrict__ rowptr,
                                                 float* __restrict__ dinv,
                                                 int* __restrict__ srcS) {
    __shared__ int sb[256];
    __shared__ int sdeg[256];
    __shared__ int lcur[256];
    int b = blockIdx.x, t = threadIdx.x;
    int n0 = b << 8;
    int gb = bucketBase[b];
    int gend = bucketBase[b + 1];

    if (t < 256) sb[t] = 0;
    __syncthreads();

    for (int idx = gb + t; idx < gend; idx += 512) atomicAdd(&sb[pairs[idx] & 255u], 1);
    __syncthreads();

    int d = (t < 256) ? sb[t] : 0;
    if (t < 256) {
        sdeg[t] = d;
        int n = n0 + t;
        if (n < NN) dinv[n] = rsqrtf((float)(d + 1));
    }
    __syncthreads();
    for (int off = 1; off < 256; off <<= 1) {
        int v = 0;
        if (t < 256 && t >= off) v = sb[t - off];
        __syncthreads();
        if (t < 256) sb[t] += v;
        __syncthreads();
    }
    if (t < 256) {
        int excl = sb[t] - sdeg[t];
        int n = n0 + t;
        if (n < NN) rowptr[n] = gb + excl;
        lcur[t] = excl;
    }
    if (b == 0 && t == 0) rowptr[NN] = EE;
    __syncthreads();

    for (int idx = gb + t; idx < gend; idx += 512) {
        u32 p = pairs[idx];
        int dl = (int)(p & 255u);
        int slot = atomicAdd(&lcur[dl], 1);
        srcS[gb + slot] = (int)(p >> 8);
    }
}

// ---------------- xs = x * dinv, bf16 (3.2 MB table, L2-resident) ----------------

__global__ void xs_k(const float* __restrict__ x, const float* __restrict__ dinv,
                     u16* __restrict__ xs) {
    int i = blockIdx.x * 256 + threadIdx.x;
    if (i >= NN * 4) return;
    int n = i >> 2;
    float dn = dinv[n];
    float4 v = ((const float4*)x)[i];
    u32 p0 = (u32)f2bf(v.x * dn) | ((u32)f2bf(v.y * dn) << 16);
    u32 p1 = (u32)f2bf(v.z * dn) | ((u32)f2bf(v.w * dn) << 16);
    uint2 pk; pk.x = p0; pk.y = p1;
    ((uint2*)xs)[i] = pk;
}

#define ACCUM8(acc, v)                       \
    {                                        \
        acc[0] += bf_lo(v.x);                \
        acc[1] += bf_hi(v.x);                \
        acc[2] += bf_lo(v.y);                \
        acc[3] += bf_hi(v.y);                \
        acc[4] += bf_lo(v.z);                \
        acc[5] += bf_hi(v.z);                \
        acc[6] += bf_lo(v.w);                \
        acc[7] += bf_hi(v.w);                \
    }

// folded reduce over lane-bit masks mA<mB<mC: 8 accs -> 1 value per lane.
#define FOLD3(res, acc, mA, mB, mC)                                   \
    {                                                                 \
        float tj[4], uj[2];                                           \
        _Pragma("unroll")                                             \
        for (int j = 0; j < 4; j++) {                                 \
            float lo = acc[j], hi = acc[j + 4];                       \
            float snd = (lane & mA) ? lo : hi;                        \
            float rcv = __shfl_xor(snd, mA);                          \
            tj[j] = (lane & mA) ? hi + rcv : lo + rcv;                \
        }                                                             \
        _Pragma("unroll")                                             \
        for (int j = 0; j < 2; j++) {                                 \
            float lo = tj[j], hi = tj[j + 2];                         \
            float snd = (lane & mB) ? lo : hi;                        \
            float rcv = __shfl_xor(snd, mB);                          \
            uj[j] = (lane & mB) ? hi + rcv : lo + rcv;                \
        }                                                             \
        {                                                             \
            float lo = uj[0], hi = uj[1];                             \
            float snd = (lane & mC) ? lo : hi;                        \
            float rcv = __shfl_xor(snd, mC);                          \
            res = (lane & mC) ? hi + rcv : lo + rcv;                  \
        }                                                             \
    }

// folded reduce, 16 accs over 4 lane-bit masks
#define FOLD4(res, acc, mA, mB, mC, mD)                               \
    {                                                                 \
        float t8[8], t4[4], t2[2];                                    \
        _Pragma("unroll")                                             \
        for (int j = 0; j < 8; j++) {                                 \
            float lo = acc[j], hi = acc[j + 8];                       \
            float snd = (lane & mA) ? lo : hi;                        \
            float rcv = __shfl_xor(snd, mA);                          \
            t8[j] = (lane & mA) ? hi + rcv : lo + rcv;                \
        }                                                             \
        _Pragma("unroll")                                             \
        for (int j = 0; j < 4; j++) {                                 \
            float lo = t8[j], hi = t8[j + 4];                         \
            float snd = (lane & mB) ? lo : hi;                        \
            float rcv = __shfl_xor(snd, mB);                          \
            t4[j] = (lane & mB) ? hi + rcv : lo + rcv;                \
        }                                                             \
        _Pragma("unroll")                                             \
        for (int j = 0; j < 2; j++) {                                 \
            float lo = t4[j], hi = t4[j + 2];                         \
            float snd = (lane & mC) ? lo : hi;                        \
            float rcv = __shfl_xor(snd, mC);                          \
            t2[j] = (lane & mC) ? hi + rcv : lo + rcv;                \
        }                                                             \
        {                                                             \
            float lo = t2[0], hi = t2[1];                             \
            float snd = (lane & mD) ? lo : hi;                        \
            float rcv = __shfl_xor(snd, mD);                          \
            res = (lane & mD) ? hi + rcv : lo + rcv;                  \
        }                                                             \
    }

// ---------------- pass 1: aggregate 16-dim xs, @W1 +b1, relu, *dinv -> h1d -----------

__global__ __launch_bounds__(256) void aggx_k(const u16* __restrict__ xs,
                                              const int* __restrict__ rowptr,
                                              const int* __restrict__ srcS,
                                              const float* __restrict__ dinv,
                                              const float* __restrict__ b1,
                                              const float* __restrict__ W1,
                                              u16* __restrict__ h1d) {
    int t = threadIdx.x;
    int lane = t & 63, w = t >> 6;
    int c = lane & 1, r = lane >> 1;
    int n0 = blockIdx.x * 8 + w * 2;
    int n1 = n0 + 1;

    float w1c[16];
#pragma unroll
    for (int k = 0; k < 16; k++) w1c[k] = W1[k * HDIM + lane];
    float b1l = b1[lane];

    int beg0 = rowptr[n0], end0 = rowptr[n0 + 1], end1 = rowptr[n0 + 2];
    int beg1 = end0;
    float dn0 = dinv[n0], dn1 = dinv[n1];

    float acc0[8] = {0, 0, 0, 0, 0, 0, 0, 0};
    float acc1[8] = {0, 0, 0, 0, 0, 0, 0, 0};
    if (r == 0) {   // self-loops
        uint4 v0 = *(const uint4*)(xs + ((size_t)n0 << 4) + (c << 3));
        uint4 v1 = *(const uint4*)(xs + ((size_t)n1 << 4) + (c << 3));
        ACCUM8(acc0, v0);
        ACCUM8(acc1, v1);
    }
    int itmax = max((end0 - beg0 + 31) >> 5, (end1 - beg1 + 31) >> 5);
    for (int it = 0; it < itmax; ++it) {
        int eA = beg0 + (it << 5) + r;
        int eB = beg1 + (it << 5) + r;
        int iA = srcS[eA < end0 ? eA : beg0];
        int iB = srcS[eB < end1 ? eB : beg1];
        uint4 vA = *(const uint4*)(xs + ((size_t)iA << 4) + (c << 3));
        uint4 vB = *(const uint4*)(xs + ((size_t)iB << 4) + (c << 3));
        if (eA < end0) ACCUM8(acc0, vA);
        if (eB < end1) ACCUM8(acc1, vB);
    }

    float v0, v1;
    FOLD3(v0, acc0, 2, 4, 8);
    FOLD3(v1, acc1, 2, 4, 8);
    v0 += __shfl_xor(v0, 16); v0 += __shfl_xor(v0, 32);
    v1 += __shfl_xor(v1, 16); v1 += __shfl_xor(v1, 32);

    float dot0 = 0.f, dot1 = 0.f;
#pragma unroll
    for (int k = 0; k < 16; k++) {
        int L = ((k >> 3) & 1) | (((k >> 2) & 1) << 1) | (((k >> 1) & 1) << 2) | ((k & 1) << 3);
        dot0 = fmaf(rdlane(v0, L), w1c[k], dot0);
        dot1 = fmaf(rdlane(v1, L), w1c[k], dot1);
    }
    float h0 = fmaxf(fmaf(dot0, dn0, b1l), 0.f);
    float h1 = fmaxf(fmaf(dot1, dn1, b1l), 0.f);

    h1d[(size_t)n0 * HDIM + lane] = f2bf(h0 * dn0);
    h1d[(size_t)n1 * HDIM + lane] = f2bf(h1 * dn1);
}

// ---------------- MFMA GEMM: h2s(fp8) = h1d @ W2  (M=NN, N=64, K=64) ----------------

__global__ __launch_bounds__(256) void gemm_w2_k(const u16* __restrict__ h1d,
                                                 const float* __restrict__ W2,
                                                 u8* __restrict__ h2s) {
    int t = threadIdx.x;
    int lane = t & 63, w = t >> 6;
    int L4 = lane >> 4, L15 = lane & 15;

    bf16x8 bfrag[4][2];
#pragma unroll
    for (int nt = 0; nt < 4; ++nt)
#pragma unroll
        for (int s = 0; s < 2; ++s) {
#pragma unroll
            for (int j = 0; j < 8; ++j) {
                int k = s * 32 + L4 * 8 + j;
                bfrag[nt][s][j] = (short)f2bf(W2[k * HDIM + nt * 16 + L15]);
            }
        }

    int tile0 = (blockIdx.x * 4 + w) * 2;
#pragma unroll
    for (int ti = 0; ti < 2; ++ti) {
        int tile = tile0 + ti;
        if (tile >= NN / 16) break;
        int node = tile * 16 + L15;
        const u16* arow = h1d + (size_t)node * HDIM + L4 * 8;
        bf16x8 a0 = *(const bf16x8*)(arow);
        bf16x8 a1 = *(const bf16x8*)(arow + 32);

        f32x4 c[4];
#pragma unroll
        for (int nt = 0; nt < 4; ++nt) {
            c[nt] = (f32x4){0.f, 0.f, 0.f, 0.f};
            c[nt] = __builtin_amdgcn_mfma_f32_16x16x32_bf16(a0, bfrag[nt][0], c[nt], 0, 0, 0);
            c[nt] = __builtin_amdgcn_mfma_f32_16x16x32_bf16(a1, bfrag[nt][1], c[nt], 0, 0, 0);
        }
#pragma unroll
        for (int q = 0; q < 4; ++q) {
            int row = L4 * 4 + q;
            size_t base = (size_t)(tile * 16 + row) * HDIM + L15;
#pragma unroll
            for (int nt = 0; nt < 4; ++nt) h2s[base + nt * 16] = f2fp8(c[nt][q]);
        }
    }
}

// ---------------- pass 2: fp8 64-dim gather + relu + pool with LDS pool reduction ----
// row = 64 B; lane: c = lane&3 (16B chunk = 16 fp8), r = lane>>2 (16 edge slots)

__global__ __launch_bounds__(512) void agg_pool_k(const u8* __restrict__ hs,
                                                  const int* __restrict__ rowptr,
                                                  const int* __restrict__ srcS,
                                                  const float* __restrict__ dinv,
                                                  const float* __restrict__ b2,
                                                  const int* __restrict__ batch,
                                                  float* __restrict__ g) {
    __shared__ float gacc[4][HDIM];
    __shared__ int s_g0, s_gmax;
    int t = threadIdx.x;
    int lane = t & 63, w = t >> 6;
    int nbase = blockIdx.x * 32;

    if (t < 4 * HDIM) gacc[t >> 6][t & 63] = 0.f;
    if (t == 0) { s_g0 = batch[nbase]; s_gmax = 0; }
    __syncthreads();
    int g0 = s_g0;

    int r = lane >> 2, c = lane & 3;
    // feature owned after FOLD4 over bits 2,3,4,5
    int f = (c << 4) + ((lane & 4) ? 8 : 0) + ((lane & 8) ? 4 : 0) +
            ((lane & 16) ? 2 : 0) + ((lane & 32) ? 1 : 0);
    float b2f = b2[f];

    for (int ni = 0; ni < 4; ++ni) {
        int n = nbase + w * 4 + ni;
        int beg = rowptr[n], end = rowptr[n + 1];
        float acc[16];
#pragma unroll
        for (int j = 0; j < 16; j++) acc[j] = 0.f;
        if (r == 0) {   // self-loop
            uint4 v = *(const uint4*)(hs + ((size_t)n << 6) + (c << 4));
            ACC16(acc, v);
        }
        for (int e0 = beg; e0 < end; e0 += 32) {
            int eA = e0 + r, eB = eA + 16;
            int iA = srcS[eA < end ? eA : beg];
            int iB = srcS[eB < end ? eB : beg];
            uint4 vA = *(const uint4*)(hs + ((size_t)iA << 6) + (c << 4));
            uint4 vB = *(const uint4*)(hs + ((size_t)iB << 6) + (c << 4));
            if (eA < end) ACC16(acc, vA);
            if (eB < end) ACC16(acc, vB);
        }
        float red;
        FOLD4(red, acc, 4, 8, 16, 32);
        float v = fmaf(red, dinv[n], b2f);
        v = fmaxf(v, 0.f);
        int gi = batch[n] - g0;
        if (gi < 4) {
            atomicAdd(&gacc[gi][f], v);
            if (lane == 0) atomicMax(&s_gmax, gi);
        } else {
            unsafeAtomicAdd(&g[(size_t)batch[n] * HDIM + f], v);
        }
    }
    __syncthreads();
    if (t < 4 * HDIM) {
        int slot = t >> 6, ff = t & 63;
        if (slot <= s_gmax) unsafeAtomicAdd(&g[(size_t)(g0 + slot) * HDIM + ff], gacc[slot][ff]);
    }
}

__global__ void final_k(const float* __restrict__ g, const float* __restrict__ Wl,
                        const float* __restrict__ bl, float* __restrict__ out) {
    int t = threadIdx.x;
    int gi = t >> 2, cc = t & 3;
    float acc = bl[cc];
#pragma unroll
    for (int k = 0; k < HDIM; k++) acc = fmaf(g[gi * HDIM + k], Wl[k * CDIM + cc], acc);
    out[gi * CDIM + cc] = acc;
}

// ---------------- launch ----------------

extern "C" void kernel_launch(void* const* d_in, const int* in_sizes, int n_in,
                              void* d_out, int out_size, void* d_ws, size_t ws_size,
                              hipStream_t stream) {
    const float* x   = (const float*)d_in[0];
    const int*   ei  = (const int*)d_in[1];
    const int*   src = ei;
    const int*   dst = ei + EE;
    const int*   batch = (const int*)d_in[2];
    const float* W1 = (const float*)d_in[3];
    const float* b1 = (const float*)d_in[4];
    const float* W2 = (const float*)d_in[5];
    const float* b2 = (const float*)d_in[6];
    const float* Wl = (const float*)d_in[7];
    const float* bl = (const float*)d_in[8];
    float* out = (float*)d_out;

    char* w = (char*)d_ws;
    auto alloc = [&](size_t bytes) -> char* {
        char* p = w;
        w += (bytes + 255) & ~(size_t)255;
        return p;
    };
    int*   bcnt       = (int*)alloc((size_t)NB * 4);
    int*   bucketBase = (int*)alloc((size_t)(NB + 1) * 4);
    int*   gcursor    = (int*)alloc((size_t)NB * 4);
    u32*   pairs      = (u32*)alloc((size_t)EE * 4);
    int*   srcS       = (int*)alloc((size_t)EE * 4);
    int*   rowptr     = (int*)alloc((size_t)(NN + 1) * 4);
    float* dinv       = (float*)alloc((size_t)NN * 4);
    u16*   xs         = (u16*)alloc((size_t)NN * IN_DIM * 2);
    u16*   h1d        = (u16*)alloc((size_t)NN * HDIM * 2);
    u8*    h2s        = (u8*)alloc((size_t)NN * HDIM + 256);
    float* g          = (float*)alloc((size_t)GG * HDIM * 4);

    hipMemsetAsync(bcnt, 0, (size_t)NB * 4, stream);
    hipMemsetAsync(g, 0, (size_t)GG * HDIM * 4, stream);

    const int NCHUNK = (EE + CH - 1) / CH;
    bhist_k<<<NCHUNK, 512, 0, stream>>>(dst, bcnt);
    bucketscan_k<<<1, 512, 0, stream>>>(bcnt, bucketBase, gcursor);
    partition_k<<<NCHUNK, 512, 0, stream>>>(src, dst, gcursor, pairs);
    csrfill_k<<<NB, 512, 0, stream>>>(bucketBase, pairs, rowptr, dinv, srcS);

    xs_k<<<(NN * 4 + 255) / 256, 256, 0, stream>>>(x, dinv, xs);
    aggx_k<<<NN / 8, 256, 0, stream>>>(xs, rowptr, srcS, dinv, b1, W1, h1d);
    gemm_w2_k<<<(NN / 16 + 7) / 8, 256, 0, stream>>>(h1d, W2, h2s);
    agg_pool_k<<<(NN + 31) / 32, 512, 0, stream>>>(h2s, rowptr, srcS, dinv, b2, batch, g);
    final_k<<<1, 512, 0, stream>>>(g, Wl, bl, out);
}